// Round 1
// baseline (1328.762 us; speedup 1.0000x reference)
//
#include <hip/hip_runtime.h>
#include <hip/hip_bf16.h>
#include <stdint.h>

// Problem: B=8, N=1024, D=768, H=12, hd=64
// Pipeline: qkv = x @ Wqkv^T (bf16 ws) -> flash attention (bf16 ctx ws) -> out = ctx @ Wproj^T + b

#define Q_ELEMS ((size_t)8192 * 2304)  // qkv ws elements (bf16)

static __device__ __forceinline__ float bf2f(unsigned short u) {
    return __uint_as_float(((unsigned int)u) << 16);
}

// ---------------- GEMM 1: qkv[8192][2304] = X[8192][768] * Wqkv[2304][768]^T (out bf16)
__global__ __launch_bounds__(256) void gemm_qkv(
    const float* __restrict__ X,
    const float* __restrict__ W,
    __hip_bfloat16* __restrict__ C) {
  __shared__ float As[16][132];   // [k][m]
  __shared__ float Bs[16][132];   // [k][n]
  const int tid = threadIdx.x;
  const int tx = tid & 15, ty = tid >> 4;
  const int i0 = blockIdx.y * 128, j0 = blockIdx.x * 128;

  float acc[8][8];
  #pragma unroll
  for (int u = 0; u < 8; u++)
    #pragma unroll
    for (int v = 0; v < 8; v++) acc[u][v] = 0.f;

  for (int kt = 0; kt < 48; kt++) {
    const int k0 = kt * 16;
    #pragma unroll
    for (int s = 0; s < 2; s++) {
      int idx = tid + s * 256;
      int row = idx >> 2, c4 = idx & 3;
      float4 va = *(const float4*)&X[(size_t)(i0 + row) * 768 + k0 + c4 * 4];
      As[c4*4+0][row] = va.x; As[c4*4+1][row] = va.y;
      As[c4*4+2][row] = va.z; As[c4*4+3][row] = va.w;
      float4 vb = *(const float4*)&W[(size_t)(j0 + row) * 768 + k0 + c4 * 4];
      Bs[c4*4+0][row] = vb.x; Bs[c4*4+1][row] = vb.y;
      Bs[c4*4+2][row] = vb.z; Bs[c4*4+3][row] = vb.w;
    }
    __syncthreads();
    #pragma unroll
    for (int kk = 0; kk < 16; kk++) {
      float4 a0 = *(const float4*)&As[kk][ty*8];
      float4 a1 = *(const float4*)&As[kk][ty*8+4];
      float4 b0 = *(const float4*)&Bs[kk][tx*8];
      float4 b1 = *(const float4*)&Bs[kk][tx*8+4];
      float a[8]  = {a0.x,a0.y,a0.z,a0.w,a1.x,a1.y,a1.z,a1.w};
      float bv[8] = {b0.x,b0.y,b0.z,b0.w,b1.x,b1.y,b1.z,b1.w};
      #pragma unroll
      for (int u = 0; u < 8; u++)
        #pragma unroll
        for (int v = 0; v < 8; v++) acc[u][v] = fmaf(a[u], bv[v], acc[u][v]);
    }
    __syncthreads();
  }
  #pragma unroll
  for (int u = 0; u < 8; u++) {
    union { uint4 u4; __hip_bfloat16 h[8]; } pack;
    #pragma unroll
    for (int v = 0; v < 8; v++) pack.h[v] = __float2bfloat16(acc[u][v]);
    *(uint4*)&C[(size_t)(i0 + ty*8 + u) * 2304 + j0 + tx*8] = pack.u4;
  }
}

// ---------------- Attention: flash-style, 1 wave = 8 query rows, block = 32 rows of one (b,h)
__global__ __launch_bounds__(256) void attn_kernel(
    const __hip_bfloat16* __restrict__ qkv,
    const int* __restrict__ mask,
    __hip_bfloat16* __restrict__ ctx) {
  __shared__ float Ks[64][65];
  __shared__ float Vs[64][65];
  __shared__ float qs[32][64];    // pre-scaled by 1/8
  __shared__ float ps[4][8][64];  // per-wave softmax weights for current chunk
  __shared__ int mks[64];
  __shared__ int mqs[32];

  const int tid = threadIdx.x;
  const int w = tid >> 6, l = tid & 63;
  const int bh = blockIdx.x >> 5;       // 0..95
  const int rb = blockIdx.x & 31;
  const int b = bh / 12, h = bh % 12;
  const int n0 = rb * 32;

  // load + scale q rows (32 x 64), and query-row mask
  {
    int rr = tid >> 3;
    int d0 = (tid & 7) * 8;
    const __hip_bfloat16* src = qkv + (size_t)(b*1024 + n0 + rr) * 2304 + h*64 + d0;
    uint4 raw = *(const uint4*)src;
    const unsigned short* us = (const unsigned short*)&raw;
    #pragma unroll
    for (int j = 0; j < 8; j++) qs[rr][d0+j] = bf2f(us[j]) * 0.125f;
    if (tid < 32) mqs[tid] = mask[b*1024 + n0 + tid];
  }
  __syncthreads();

  float m_run[8], lsum[8], o[8];
  #pragma unroll
  for (int r = 0; r < 8; r++) { m_run[r] = -1e30f; lsum[r] = 0.f; o[r] = 0.f; }

  for (int c = 0; c < 16; c++) {
    // stage K,V chunk (64 keys x 64 dims) + key mask
    {
      int jj = tid >> 3;
      int d0 = (tid & 7) * 8;
      #pragma unroll
      for (int s = 0; s < 2; s++) {
        int key = c*64 + jj + s*32;
        const __hip_bfloat16* kp = qkv + (size_t)(b*1024 + key) * 2304 + 768 + h*64 + d0;
        uint4 rk = *(const uint4*)kp;
        const unsigned short* uk = (const unsigned short*)&rk;
        #pragma unroll
        for (int j = 0; j < 8; j++) Ks[jj + s*32][d0+j] = bf2f(uk[j]);
        uint4 rv = *(const uint4*)(kp + 768);
        const unsigned short* uv = (const unsigned short*)&rv;
        #pragma unroll
        for (int j = 0; j < 8; j++) Vs[jj + s*32][d0+j] = bf2f(uv[j]);
      }
      if (tid < 64) mks[tid] = mask[b*1024 + c*64 + tid];
    }
    __syncthreads();

    // QK^T for 8 rows: lane l owns key c*64+l
    float sacc[8];
    #pragma unroll
    for (int r = 0; r < 8; r++) sacc[r] = 0.f;
    #pragma unroll 4
    for (int dg = 0; dg < 16; dg++) {
      const float k0v = Ks[l][dg*4+0];
      const float k1v = Ks[l][dg*4+1];
      const float k2v = Ks[l][dg*4+2];
      const float k3v = Ks[l][dg*4+3];
      #pragma unroll
      for (int r = 0; r < 8; r++) {
        const float4 q4 = *(const float4*)&qs[w*8+r][dg*4];
        sacc[r] = fmaf(q4.x,k0v, fmaf(q4.y,k1v, fmaf(q4.z,k2v, fmaf(q4.w,k3v, sacc[r]))));
      }
    }

    // online softmax per row
    #pragma unroll
    for (int r = 0; r < 8; r++) {
      const int rr = w*8 + r;
      const int n = n0 + rr;
      const int mq = mqs[rr];
      const int mk = mks[l];
      const int mg = c*64 + l;
      const bool keep = (mq && mk) || (!mq && (mg == n));
      float sv = keep ? sacc[r] : -1e30f;
      float red = sv;
      #pragma unroll
      for (int off = 32; off; off >>= 1) red = fmaxf(red, __shfl_xor(red, off));
      float mnew = fmaxf(m_run[r], red);
      float alpha = __expf(m_run[r] - mnew);
      m_run[r] = mnew;
      float e = keep ? __expf(sacc[r] - mnew) : 0.f;
      float rs = e;
      #pragma unroll
      for (int off = 32; off; off >>= 1) rs += __shfl_xor(rs, off);
      lsum[r] = lsum[r] * alpha + rs;
      o[r] *= alpha;
      ps[w][r][l] = e;   // same-wave LDS write->read, in-order on CDNA
    }

    // PV: lane l owns output dim l
    #pragma unroll 4
    for (int jg = 0; jg < 16; jg++) {
      float4 pv[8];
      #pragma unroll
      for (int r = 0; r < 8; r++) pv[r] = *(const float4*)&ps[w][r][jg*4];
      #pragma unroll
      for (int jj = 0; jj < 4; jj++) {
        float vv = Vs[jg*4 + jj][l];
        #pragma unroll
        for (int r = 0; r < 8; r++) {
          const float* pp = (const float*)&pv[r];
          o[r] = fmaf(pp[jj], vv, o[r]);
        }
      }
    }
    __syncthreads();
  }

  #pragma unroll
  for (int r = 0; r < 8; r++) {
    const int n = n0 + w*8 + r;
    float val = o[r] / lsum[r];
    ctx[(size_t)(b*1024 + n) * 768 + h*64 + l] = __float2bfloat16(val);
  }
}

// ---------------- GEMM 2: out[8192][768] = ctx[8192][768](bf16) * Wproj[768][768]^T + bias (out fp32)
__global__ __launch_bounds__(256) void gemm_proj(
    const __hip_bfloat16* __restrict__ Actx,
    const float* __restrict__ W,
    const float* __restrict__ bias,
    float* __restrict__ Out) {
  __shared__ float As[16][132];
  __shared__ float Bs[16][132];
  const int tid = threadIdx.x;
  const int tx = tid & 15, ty = tid >> 4;
  const int i0 = blockIdx.y * 128, j0 = blockIdx.x * 128;

  float acc[8][8];
  #pragma unroll
  for (int u = 0; u < 8; u++)
    #pragma unroll
    for (int v = 0; v < 8; v++) acc[u][v] = 0.f;

  for (int kt = 0; kt < 48; kt++) {
    const int k0 = kt * 16;
    {
      int row = tid >> 1, c8 = (tid & 1) * 8;
      uint4 raw = *(const uint4*)&Actx[(size_t)(i0 + row) * 768 + k0 + c8];
      const unsigned short* us = (const unsigned short*)&raw;
      #pragma unroll
      for (int j = 0; j < 8; j++) As[c8 + j][row] = bf2f(us[j]);
    }
    #pragma unroll
    for (int s = 0; s < 2; s++) {
      int idx = tid + s * 256;
      int row = idx >> 2, c4 = idx & 3;
      float4 vb = *(const float4*)&W[(size_t)(j0 + row) * 768 + k0 + c4 * 4];
      Bs[c4*4+0][row] = vb.x; Bs[c4*4+1][row] = vb.y;
      Bs[c4*4+2][row] = vb.z; Bs[c4*4+3][row] = vb.w;
    }
    __syncthreads();
    #pragma unroll
    for (int kk = 0; kk < 16; kk++) {
      float4 a0 = *(const float4*)&As[kk][ty*8];
      float4 a1 = *(const float4*)&As[kk][ty*8+4];
      float4 b0 = *(const float4*)&Bs[kk][tx*8];
      float4 b1 = *(const float4*)&Bs[kk][tx*8+4];
      float a[8]  = {a0.x,a0.y,a0.z,a0.w,a1.x,a1.y,a1.z,a1.w};
      float bv[8] = {b0.x,b0.y,b0.z,b0.w,b1.x,b1.y,b1.z,b1.w};
      #pragma unroll
      for (int u = 0; u < 8; u++)
        #pragma unroll
        for (int v = 0; v < 8; v++) acc[u][v] = fmaf(a[u], bv[v], acc[u][v]);
    }
    __syncthreads();
  }
  float4 bb0 = *(const float4*)&bias[j0 + tx*8];
  float4 bb1 = *(const float4*)&bias[j0 + tx*8 + 4];
  #pragma unroll
  for (int u = 0; u < 8; u++) {
    float4 o0, o1;
    o0.x = acc[u][0] + bb0.x; o0.y = acc[u][1] + bb0.y;
    o0.z = acc[u][2] + bb0.z; o0.w = acc[u][3] + bb0.w;
    o1.x = acc[u][4] + bb1.x; o1.y = acc[u][5] + bb1.y;
    o1.z = acc[u][6] + bb1.z; o1.w = acc[u][7] + bb1.w;
    float* dst = &Out[(size_t)(i0 + ty*8 + u) * 768 + j0 + tx*8];
    *(float4*)dst = o0;
    *(float4*)(dst + 4) = o1;
  }
}

extern "C" void kernel_launch(void* const* d_in, const int* in_sizes, int n_in,
                              void* d_out, int out_size, void* d_ws, size_t ws_size,
                              hipStream_t stream) {
  const float* x     = (const float*)d_in[0];
  const int*   mask  = (const int*)d_in[1];
  const float* Wqkv  = (const float*)d_in[2];
  const float* Wproj = (const float*)d_in[3];
  const float* bproj = (const float*)d_in[4];
  float* out = (float*)d_out;

  char* wsb = (char*)d_ws;
  __hip_bfloat16* qkv = (__hip_bfloat16*)wsb;                      // 8192*2304 bf16 = 37.75 MB
  __hip_bfloat16* ctx = (__hip_bfloat16*)(wsb + Q_ELEMS * 2);      // 8192*768 bf16 = 12.58 MB

  gemm_qkv<<<dim3(18, 64), 256, 0, stream>>>(x, Wqkv, qkv);
  attn_kernel<<<dim3(3072), 256, 0, stream>>>(qkv, mask, ctx);
  gemm_proj<<<dim3(6, 64), 256, 0, stream>>>(ctx, Wproj, bproj, out);
}

// Round 2
// 620.803 us; speedup vs baseline: 2.1404x; 2.1404x over previous
//
#include <hip/hip_runtime.h>
#include <hip/hip_bf16.h>
#include <stdint.h>

// B=8, N=1024, D=768, H=12, hd=64
// qkv = x @ Wqkv^T (bf16 ws) -> MFMA flash attention (bf16 ctx ws) -> out = ctx @ Wproj^T + b

#define Q_ELEMS ((size_t)8192 * 2304)

typedef unsigned short u16;
typedef __attribute__((ext_vector_type(8))) short short8;
typedef __attribute__((ext_vector_type(4))) float f32x4;

#define MFMA16(a, b, c) __builtin_amdgcn_mfma_f32_16x16x32_bf16((a), (b), (c), 0, 0, 0)

static __device__ __forceinline__ float bf2f(u16 u) {
    return __uint_as_float(((unsigned int)u) << 16);
}
static __device__ __forceinline__ u16 f2bf(float f) {
    __hip_bfloat16 h = __float2bfloat16(f);
    return *(u16*)&h;
}

// ---------------- GEMM 1: qkv[8192][2304] = X[8192][768] * Wqkv[2304][768]^T (out bf16)
__global__ __launch_bounds__(256) void gemm_qkv(
    const float* __restrict__ X,
    const float* __restrict__ W,
    __hip_bfloat16* __restrict__ C) {
  __shared__ float As[16][132];   // [k][m]
  __shared__ float Bs[16][132];   // [k][n]
  const int tid = threadIdx.x;
  const int tx = tid & 15, ty = tid >> 4;
  const int i0 = blockIdx.y * 128, j0 = blockIdx.x * 128;

  float acc[8][8];
  #pragma unroll
  for (int u = 0; u < 8; u++)
    #pragma unroll
    for (int v = 0; v < 8; v++) acc[u][v] = 0.f;

  for (int kt = 0; kt < 48; kt++) {
    const int k0 = kt * 16;
    #pragma unroll
    for (int s = 0; s < 2; s++) {
      int idx = tid + s * 256;
      int row = idx >> 2, c4 = idx & 3;
      float4 va = *(const float4*)&X[(size_t)(i0 + row) * 768 + k0 + c4 * 4];
      As[c4*4+0][row] = va.x; As[c4*4+1][row] = va.y;
      As[c4*4+2][row] = va.z; As[c4*4+3][row] = va.w;
      float4 vb = *(const float4*)&W[(size_t)(j0 + row) * 768 + k0 + c4 * 4];
      Bs[c4*4+0][row] = vb.x; Bs[c4*4+1][row] = vb.y;
      Bs[c4*4+2][row] = vb.z; Bs[c4*4+3][row] = vb.w;
    }
    __syncthreads();
    #pragma unroll
    for (int kk = 0; kk < 16; kk++) {
      float4 a0 = *(const float4*)&As[kk][ty*8];
      float4 a1 = *(const float4*)&As[kk][ty*8+4];
      float4 b0 = *(const float4*)&Bs[kk][tx*8];
      float4 b1 = *(const float4*)&Bs[kk][tx*8+4];
      float a[8]  = {a0.x,a0.y,a0.z,a0.w,a1.x,a1.y,a1.z,a1.w};
      float bv[8] = {b0.x,b0.y,b0.z,b0.w,b1.x,b1.y,b1.z,b1.w};
      #pragma unroll
      for (int u = 0; u < 8; u++)
        #pragma unroll
        for (int v = 0; v < 8; v++) acc[u][v] = fmaf(a[u], bv[v], acc[u][v]);
    }
    __syncthreads();
  }
  #pragma unroll
  for (int u = 0; u < 8; u++) {
    union { uint4 u4; __hip_bfloat16 h[8]; } pack;
    #pragma unroll
    for (int v = 0; v < 8; v++) pack.h[v] = __float2bfloat16(acc[u][v]);
    *(uint4*)&C[(size_t)(i0 + ty*8 + u) * 2304 + j0 + tx*8] = pack.u4;
  }
}

// ---------------- Attention: MFMA flash, fixed-max softmax.
// Block = 256 thr (4 waves), 128 query rows (32/wave), grid = 96*(1024/128)=768.
__global__ __launch_bounds__(256, 3) void attn_mfma(
    const u16* __restrict__ qkv,   // bf16 bits, [B*N][2304]; q at +0, k at +768, v at +1536 (+h*64)
    const int* __restrict__ mask,
    u16* __restrict__ ctx) {
  __shared__ u16 Ks[64][72];      // [key][dim], stride 36 banks
  __shared__ u16 Vt[64][72];      // [dim][key]
  __shared__ u16 Ps[4][32][72];   // per-wave P tile [local row][key]
  __shared__ float mkb[64];       // 0 or -1e38 (log2-domain additive mask)
  __shared__ int mqs[128];

  const int tid = threadIdx.x;
  const int w = tid >> 6, l = tid & 63;
  const int lane16 = l & 15, quad = l >> 4;
  const int bh = blockIdx.x >> 3, rb = blockIdx.x & 7;
  const int b = bh / 12, h = bh % 12;
  const int n0 = rb * 128;
  const int baseRow = b * 1024;

  if (tid < 128) mqs[tid] = mask[baseRow + n0 + tid];

  // Q fragments in registers, A-layout: m=lane16 (row), k=quad*8+j. Raw (scale folded into exp).
  short8 qfrag[2][2];
  #pragma unroll
  for (int mt = 0; mt < 2; mt++) {
    const u16* qp = qkv + (size_t)(baseRow + n0 + w*32 + mt*16 + lane16) * 2304 + h*64;
    #pragma unroll
    for (int ks = 0; ks < 2; ks++)
      qfrag[mt][ks] = *(const short8*)(qp + ks*32 + quad*8);
  }

  f32x4 oacc[2][4];
  #pragma unroll
  for (int mt = 0; mt < 2; mt++)
    #pragma unroll
    for (int nt = 0; nt < 4; nt++) oacc[mt][nt] = (f32x4){0.f, 0.f, 0.f, 0.f};
  float lsum[2][4];
  #pragma unroll
  for (int mt = 0; mt < 2; mt++)
    #pragma unroll
    for (int r = 0; r < 4; r++) lsum[mt][r] = 0.f;

  __syncthreads();
  int mqbits = 0;
  #pragma unroll
  for (int mt = 0; mt < 2; mt++)
    #pragma unroll
    for (int r = 0; r < 4; r++)
      mqbits |= (mqs[w*32 + mt*16 + quad*4 + r] ? 1 : 0) << (mt*4 + r);

  // exp(s/8 - 16) == exp2(s*K1 + K0); fixed max 16 >> max score (~8 sigma), overflow-free.
  const float K1 = 0.18033688011112043f;   // log2(e)/8
  const float K0 = -23.083120654223415f;   // -16*log2(e)

  for (int c = 0; c < 16; c++) {
    __syncthreads();   // prior iter's Ks/Vt reads done before overwrite
    {
      // K: thread -> key=tid>>2, 16 dims; natural layout, b128 writes (2-way = free)
      int key = tid >> 2, ds = (tid & 3) * 16;
      const u16* kp = qkv + (size_t)(baseRow + c*64 + key) * 2304 + 768 + h*64 + ds;
      *(uint4*)&Ks[key][ds]     = *(const uint4*)kp;
      *(uint4*)&Ks[key][ds + 8] = *(const uint4*)(kp + 8);
      // V transposed: lane-major keypair => conflict-free packed b32 writes
      int kA = (tid & 31) * 2, dg = tid >> 5;   // dg 0..7
      const u16* vp = qkv + (size_t)(baseRow + c*64 + kA) * 2304 + 1536 + h*64 + dg*8;
      uint4 r0 = *(const uint4*)vp;
      uint4 r1 = *(const uint4*)(vp + 2304);
      const u16* va = (const u16*)&r0;
      const u16* vb = (const u16*)&r1;
      #pragma unroll
      for (int j = 0; j < 8; j++)
        *(unsigned int*)&Vt[dg*8 + j][kA] = (unsigned int)va[j] | ((unsigned int)vb[j] << 16);
      if (tid < 64) mkb[tid] = mask[baseRow + c*64 + tid] ? 0.f : -1e38f;
    }
    __syncthreads();

    // QK^T: S[32 x 64] per wave. A=Q(regs), B=K^T from Ks (B-frag: n=key=t*16+lane16, k=dim).
    f32x4 sacc[2][4];
    #pragma unroll
    for (int mt = 0; mt < 2; mt++)
      #pragma unroll
      for (int t = 0; t < 4; t++) sacc[mt][t] = (f32x4){0.f, 0.f, 0.f, 0.f};
    #pragma unroll
    for (int ks = 0; ks < 2; ks++) {
      short8 kf[4];
      #pragma unroll
      for (int t = 0; t < 4; t++)
        kf[t] = *(const short8*)&Ks[t*16 + lane16][ks*32 + quad*8];
      #pragma unroll
      for (int mt = 0; mt < 2; mt++)
        #pragma unroll
        for (int t = 0; t < 4; t++)
          sacc[mt][t] = MFMA16(qfrag[mt][ks], kf[t], sacc[mt][t]);
    }

    // softmax (no reductions): C-layout col=lane16, row=quad*4+r
    #pragma unroll
    for (int t = 0; t < 4; t++) {
      float bias = mkb[t*16 + lane16];
      int cg = c*64 + t*16 + lane16;
      #pragma unroll
      for (int mt = 0; mt < 2; mt++) {
        #pragma unroll
        for (int r = 0; r < 4; r++) {
          float e = __builtin_amdgcn_exp2f(fmaf(sacc[mt][t][r], K1, K0) + bias);
          int rg = n0 + w*32 + mt*16 + quad*4 + r;
          if (!((mqbits >> (mt*4 + r)) & 1)) e = (cg == rg) ? 1.0f : 0.0f;
          lsum[mt][r] += e;
          Ps[w][mt*16 + quad*4 + r][t*16 + lane16] = f2bf(e);
        }
      }
    }

    // PV: O += P[32x64] * V[64x64]. A=P (own-wave LDS, no barrier), B=V from Vt.
    #pragma unroll
    for (int kc = 0; kc < 2; kc++) {
      short8 pf[2], vf[4];
      #pragma unroll
      for (int mt = 0; mt < 2; mt++)
        pf[mt] = *(const short8*)&Ps[w][mt*16 + lane16][kc*32 + quad*8];
      #pragma unroll
      for (int nt = 0; nt < 4; nt++)
        vf[nt] = *(const short8*)&Vt[nt*16 + lane16][kc*32 + quad*8];
      #pragma unroll
      for (int mt = 0; mt < 2; mt++)
        #pragma unroll
        for (int nt = 0; nt < 4; nt++)
          oacc[mt][nt] = MFMA16(pf[mt], vf[nt], oacc[mt][nt]);
    }
  }

  // final row-sum reduce (cols live in the 16-lane group) + normalize + store
  float linv[2][4];
  #pragma unroll
  for (int mt = 0; mt < 2; mt++)
    #pragma unroll
    for (int r = 0; r < 4; r++) {
      float s = lsum[mt][r];
      s += __shfl_xor(s, 1); s += __shfl_xor(s, 2);
      s += __shfl_xor(s, 4); s += __shfl_xor(s, 8);
      linv[mt][r] = 1.0f / s;
    }
  #pragma unroll
  for (int mt = 0; mt < 2; mt++) {
    #pragma unroll
    for (int nt = 0; nt < 4; nt++) {
      #pragma unroll
      for (int r = 0; r < 4; r++) {
        int rg = n0 + w*32 + mt*16 + quad*4 + r;
        ctx[(size_t)(baseRow + rg) * 768 + h*64 + nt*16 + lane16] =
            f2bf(oacc[mt][nt][r] * linv[mt][r]);
      }
    }
  }
}

// ---------------- GEMM 2: out[8192][768] = ctx[8192][768](bf16) * Wproj[768][768]^T + bias (fp32)
__global__ __launch_bounds__(256) void gemm_proj(
    const __hip_bfloat16* __restrict__ Actx,
    const float* __restrict__ W,
    const float* __restrict__ bias,
    float* __restrict__ Out) {
  __shared__ float As[16][132];
  __shared__ float Bs[16][132];
  const int tid = threadIdx.x;
  const int tx = tid & 15, ty = tid >> 4;
  const int i0 = blockIdx.y * 128, j0 = blockIdx.x * 128;

  float acc[8][8];
  #pragma unroll
  for (int u = 0; u < 8; u++)
    #pragma unroll
    for (int v = 0; v < 8; v++) acc[u][v] = 0.f;

  for (int kt = 0; kt < 48; kt++) {
    const int k0 = kt * 16;
    {
      int row = tid >> 1, c8 = (tid & 1) * 8;
      uint4 raw = *(const uint4*)&Actx[(size_t)(i0 + row) * 768 + k0 + c8];
      const u16* us = (const u16*)&raw;
      #pragma unroll
      for (int j = 0; j < 8; j++) As[c8 + j][row] = bf2f(us[j]);
    }
    #pragma unroll
    for (int s = 0; s < 2; s++) {
      int idx = tid + s * 256;
      int row = idx >> 2, c4 = idx & 3;
      float4 vb = *(const float4*)&W[(size_t)(j0 + row) * 768 + k0 + c4 * 4];
      Bs[c4*4+0][row] = vb.x; Bs[c4*4+1][row] = vb.y;
      Bs[c4*4+2][row] = vb.z; Bs[c4*4+3][row] = vb.w;
    }
    __syncthreads();
    #pragma unroll
    for (int kk = 0; kk < 16; kk++) {
      float4 a0 = *(const float4*)&As[kk][ty*8];
      float4 a1 = *(const float4*)&As[kk][ty*8+4];
      float4 b0 = *(const float4*)&Bs[kk][tx*8];
      float4 b1 = *(const float4*)&Bs[kk][tx*8+4];
      float a[8]  = {a0.x,a0.y,a0.z,a0.w,a1.x,a1.y,a1.z,a1.w};
      float bv[8] = {b0.x,b0.y,b0.z,b0.w,b1.x,b1.y,b1.z,b1.w};
      #pragma unroll
      for (int u = 0; u < 8; u++)
        #pragma unroll
        for (int v = 0; v < 8; v++) acc[u][v] = fmaf(a[u], bv[v], acc[u][v]);
    }
    __syncthreads();
  }
  float4 bb0 = *(const float4*)&bias[j0 + tx*8];
  float4 bb1 = *(const float4*)&bias[j0 + tx*8 + 4];
  #pragma unroll
  for (int u = 0; u < 8; u++) {
    float4 o0, o1;
    o0.x = acc[u][0] + bb0.x; o0.y = acc[u][1] + bb0.y;
    o0.z = acc[u][2] + bb0.z; o0.w = acc[u][3] + bb0.w;
    o1.x = acc[u][4] + bb1.x; o1.y = acc[u][5] + bb1.y;
    o1.z = acc[u][6] + bb1.z; o1.w = acc[u][7] + bb1.w;
    float* dst = &Out[(size_t)(i0 + ty*8 + u) * 768 + j0 + tx*8];
    *(float4*)dst = o0;
    *(float4*)(dst + 4) = o1;
  }
}

extern "C" void kernel_launch(void* const* d_in, const int* in_sizes, int n_in,
                              void* d_out, int out_size, void* d_ws, size_t ws_size,
                              hipStream_t stream) {
  const float* x     = (const float*)d_in[0];
  const int*   mask  = (const int*)d_in[1];
  const float* Wqkv  = (const float*)d_in[2];
  const float* Wproj = (const float*)d_in[3];
  const float* bproj = (const float*)d_in[4];
  float* out = (float*)d_out;

  char* wsb = (char*)d_ws;
  __hip_bfloat16* qkv = (__hip_bfloat16*)wsb;                      // 37.75 MB
  __hip_bfloat16* ctx = (__hip_bfloat16*)(wsb + Q_ELEMS * 2);      // 12.58 MB

  gemm_qkv<<<dim3(18, 64), 256, 0, stream>>>(x, Wqkv, qkv);
  attn_mfma<<<dim3(768), 256, 0, stream>>>((const u16*)qkv, mask, (u16*)ctx);
  gemm_proj<<<dim3(6, 64), 256, 0, stream>>>(ctx, Wproj, bproj, out);
}

// Round 3
// 207.528 us; speedup vs baseline: 6.4028x; 2.9914x over previous
//
#include <hip/hip_runtime.h>
#include <hip/hip_bf16.h>
#include <stdint.h>

// B=8, N=1024, D=768, H=12, hd=64
// cvt(x,Wqkv,Wproj -> bf16 ws) -> MFMA gemm qkv -> MFMA flash attention -> MFMA gemm proj + bias

typedef unsigned short u16;
typedef __attribute__((ext_vector_type(8))) short short8;
typedef __attribute__((ext_vector_type(4))) float f32x4;

#define MFMA16(a, b, c) __builtin_amdgcn_mfma_f32_16x16x32_bf16((a), (b), (c), 0, 0, 0)

static __device__ __forceinline__ float bf2f(u16 u) {
    return __uint_as_float(((unsigned int)u) << 16);
}
static __device__ __forceinline__ u16 f2bf(float f) {
    __hip_bfloat16 h = __float2bfloat16(f);
    return *(u16*)&h;
}
// async global->LDS, 16B per lane; LDS dest must be wave-uniform-base + lane*16
static __device__ __forceinline__ void gld16(const u16* g, u16* l) {
  __builtin_amdgcn_global_load_lds(
      (const __attribute__((address_space(1))) void*)g,
      (__attribute__((address_space(3))) void*)l, 16, 0, 0);
}

// ---------------- fp32 -> bf16 conversion of the three input tensors
__global__ __launch_bounds__(256) void cvt_bf16(
    const float* __restrict__ s0, u16* __restrict__ d0, int n0,
    const float* __restrict__ s1, u16* __restrict__ d1, int n1,
    const float* __restrict__ s2, u16* __restrict__ d2, int n2) {
  int i = (blockIdx.x * 256 + threadIdx.x) * 4;
  const float* s; u16* d;
  if (i < n0) { s = s0 + i; d = d0 + i; }
  else if ((i -= n0) < n1) { s = s1 + i; d = d1 + i; }
  else if ((i -= n1) < n2) { s = s2 + i; d = d2 + i; }
  else return;
  float4 v = *(const float4*)s;
  ushort4 o;
  o.x = f2bf(v.x); o.y = f2bf(v.y); o.z = f2bf(v.z); o.w = f2bf(v.w);
  *(ushort4*)d = o;
}

// ---------------- MFMA GEMM: C[M][LDC] = A[M][K](bf16) * B[N][K](bf16)^T
// m97 structure: 128x128 tile, BK=32, 4 waves each 64x64 (4x4 of 16x16x32).
template<int K, int LDC, bool BF16OUT>
__global__ __launch_bounds__(256) void gemm_bt(
    const u16* __restrict__ A,
    const u16* __restrict__ B,
    void* __restrict__ Cout,
    const float* __restrict__ bias) {
  __shared__ u16 As[128 * 32];
  __shared__ u16 Bs[128 * 32];
  const int tid = threadIdx.x;
  const int w = tid >> 6, l = tid & 63;
  const int lane16 = l & 15, quad = l >> 4;
  const int i0 = blockIdx.y * 128, j0 = blockIdx.x * 128;
  const int mh = (w & 1) * 64;    // wave's m-offset within tile
  const int nh = (w >> 1) * 64;   // wave's n-offset within tile

  f32x4 acc[4][4];
  #pragma unroll
  for (int mt = 0; mt < 4; mt++)
    #pragma unroll
    for (int nt = 0; nt < 4; nt++) acc[mt][nt] = (f32x4){0.f, 0.f, 0.f, 0.f};

  for (int kt = 0; kt < K / 32; kt++) {
    const int k0 = kt * 32;
    __syncthreads();   // prior iter's LDS reads complete before overwrite
    #pragma unroll
    for (int s = 0; s < 2; s++) {
      int idx = tid + s * 256;
      int row = idx >> 2, c8 = (idx & 3) * 8;
      gld16(&A[(size_t)(i0 + row) * K + k0 + c8], &As[row * 32 + c8]);
      gld16(&B[(size_t)(j0 + row) * K + k0 + c8], &Bs[row * 32 + c8]);
    }
    __syncthreads();   // drain global_load_lds (compiler emits vmcnt(0) here)

    short8 af[4], bf[4];
    #pragma unroll
    for (int mt = 0; mt < 4; mt++)
      af[mt] = *(const short8*)&As[(mh + mt * 16 + lane16) * 32 + quad * 8];
    #pragma unroll
    for (int nt = 0; nt < 4; nt++)
      bf[nt] = *(const short8*)&Bs[(nh + nt * 16 + lane16) * 32 + quad * 8];
    #pragma unroll
    for (int mt = 0; mt < 4; mt++)
      #pragma unroll
      for (int nt = 0; nt < 4; nt++)
        acc[mt][nt] = MFMA16(af[mt], bf[nt], acc[mt][nt]);
  }

  // epilogue: C-layout col=lane16, row=quad*4+r
  #pragma unroll
  for (int mt = 0; mt < 4; mt++) {
    #pragma unroll
    for (int nt = 0; nt < 4; nt++) {
      int col = j0 + nh + nt * 16 + lane16;
      #pragma unroll
      for (int r = 0; r < 4; r++) {
        int row = i0 + mh + mt * 16 + quad * 4 + r;
        if (BF16OUT) {
          ((u16*)Cout)[(size_t)row * LDC + col] = f2bf(acc[mt][nt][r]);
        } else {
          ((float*)Cout)[(size_t)row * LDC + col] = acc[mt][nt][r] + bias[col];
        }
      }
    }
  }
}

// ---------------- Attention: MFMA flash, fixed-max softmax.
// Block = 256 thr (4 waves), 128 query rows (32/wave), grid = 96*(1024/128)=768.
__global__ __launch_bounds__(256, 3) void attn_mfma(
    const u16* __restrict__ qkv,   // bf16 bits, [B*N][2304]; q at +0, k at +768, v at +1536 (+h*64)
    const int* __restrict__ mask,
    u16* __restrict__ ctx) {
  __shared__ u16 Ks[64][72];      // [key][dim], stride 36 banks
  __shared__ u16 Vt[64][72];      // [dim][key]
  __shared__ u16 Ps[4][32][72];   // per-wave P tile [local row][key]
  __shared__ float mkb[64];       // 0 or -1e38 (log2-domain additive mask)
  __shared__ int mqs[128];

  const int tid = threadIdx.x;
  const int w = tid >> 6, l = tid & 63;
  const int lane16 = l & 15, quad = l >> 4;
  const int bh = blockIdx.x >> 3, rb = blockIdx.x & 7;
  const int b = bh / 12, h = bh % 12;
  const int n0 = rb * 128;
  const int baseRow = b * 1024;

  if (tid < 128) mqs[tid] = mask[baseRow + n0 + tid];

  // Q fragments in registers, A-layout: m=lane16 (row), k=quad*8+j. Raw (scale folded into exp).
  short8 qfrag[2][2];
  #pragma unroll
  for (int mt = 0; mt < 2; mt++) {
    const u16* qp = qkv + (size_t)(baseRow + n0 + w*32 + mt*16 + lane16) * 2304 + h*64;
    #pragma unroll
    for (int ks = 0; ks < 2; ks++)
      qfrag[mt][ks] = *(const short8*)(qp + ks*32 + quad*8);
  }

  f32x4 oacc[2][4];
  #pragma unroll
  for (int mt = 0; mt < 2; mt++)
    #pragma unroll
    for (int nt = 0; nt < 4; nt++) oacc[mt][nt] = (f32x4){0.f, 0.f, 0.f, 0.f};
  float lsum[2][4];
  #pragma unroll
  for (int mt = 0; mt < 2; mt++)
    #pragma unroll
    for (int r = 0; r < 4; r++) lsum[mt][r] = 0.f;

  __syncthreads();
  int mqbits = 0;
  #pragma unroll
  for (int mt = 0; mt < 2; mt++)
    #pragma unroll
    for (int r = 0; r < 4; r++)
      mqbits |= (mqs[w*32 + mt*16 + quad*4 + r] ? 1 : 0) << (mt*4 + r);

  // exp(s/8 - 16) == exp2(s*K1 + K0); fixed max 16 >> max score (~8 sigma), overflow-free.
  const float K1 = 0.18033688011112043f;   // log2(e)/8
  const float K0 = -23.083120654223415f;   // -16*log2(e)

  for (int c = 0; c < 16; c++) {
    __syncthreads();   // prior iter's Ks/Vt reads done before overwrite
    {
      // K: thread -> key=tid>>2, 16 dims; natural layout, b128 writes (2-way = free)
      int key = tid >> 2, ds = (tid & 3) * 16;
      const u16* kp = qkv + (size_t)(baseRow + c*64 + key) * 2304 + 768 + h*64 + ds;
      *(uint4*)&Ks[key][ds]     = *(const uint4*)kp;
      *(uint4*)&Ks[key][ds + 8] = *(const uint4*)(kp + 8);
      // V transposed: lane-major keypair => conflict-free packed b32 writes
      int kA = (tid & 31) * 2, dg = tid >> 5;   // dg 0..7
      const u16* vp = qkv + (size_t)(baseRow + c*64 + kA) * 2304 + 1536 + h*64 + dg*8;
      uint4 r0 = *(const uint4*)vp;
      uint4 r1 = *(const uint4*)(vp + 2304);
      const u16* va = (const u16*)&r0;
      const u16* vb = (const u16*)&r1;
      #pragma unroll
      for (int j = 0; j < 8; j++)
        *(unsigned int*)&Vt[dg*8 + j][kA] = (unsigned int)va[j] | ((unsigned int)vb[j] << 16);
      if (tid < 64) mkb[tid] = mask[baseRow + c*64 + tid] ? 0.f : -1e38f;
    }
    __syncthreads();

    // QK^T: S[32 x 64] per wave. A=Q(regs), B=K^T from Ks (B-frag: n=key=t*16+lane16, k=dim).
    f32x4 sacc[2][4];
    #pragma unroll
    for (int mt = 0; mt < 2; mt++)
      #pragma unroll
      for (int t = 0; t < 4; t++) sacc[mt][t] = (f32x4){0.f, 0.f, 0.f, 0.f};
    #pragma unroll
    for (int ks = 0; ks < 2; ks++) {
      short8 kf[4];
      #pragma unroll
      for (int t = 0; t < 4; t++)
        kf[t] = *(const short8*)&Ks[t*16 + lane16][ks*32 + quad*8];
      #pragma unroll
      for (int mt = 0; mt < 2; mt++)
        #pragma unroll
        for (int t = 0; t < 4; t++)
          sacc[mt][t] = MFMA16(qfrag[mt][ks], kf[t], sacc[mt][t]);
    }

    // softmax (no reductions): C-layout col=lane16, row=quad*4+r
    #pragma unroll
    for (int t = 0; t < 4; t++) {
      float bias = mkb[t*16 + lane16];
      int cg = c*64 + t*16 + lane16;
      #pragma unroll
      for (int mt = 0; mt < 2; mt++) {
        #pragma unroll
        for (int r = 0; r < 4; r++) {
          float e = __builtin_amdgcn_exp2f(fmaf(sacc[mt][t][r], K1, K0) + bias);
          int rg = n0 + w*32 + mt*16 + quad*4 + r;
          if (!((mqbits >> (mt*4 + r)) & 1)) e = (cg == rg) ? 1.0f : 0.0f;
          lsum[mt][r] += e;
          Ps[w][mt*16 + quad*4 + r][t*16 + lane16] = f2bf(e);
        }
      }
    }

    // PV: O += P[32x64] * V[64x64]. A=P (own-wave LDS, no barrier), B=V from Vt.
    #pragma unroll
    for (int kc = 0; kc < 2; kc++) {
      short8 pf[2], vf[4];
      #pragma unroll
      for (int mt = 0; mt < 2; mt++)
        pf[mt] = *(const short8*)&Ps[w][mt*16 + lane16][kc*32 + quad*8];
      #pragma unroll
      for (int nt = 0; nt < 4; nt++)
        vf[nt] = *(const short8*)&Vt[nt*16 + lane16][kc*32 + quad*8];
      #pragma unroll
      for (int mt = 0; mt < 2; mt++)
        #pragma unroll
        for (int nt = 0; nt < 4; nt++)
          oacc[mt][nt] = MFMA16(pf[mt], vf[nt], oacc[mt][nt]);
    }
  }

  // final row-sum reduce (cols live in the 16-lane group) + normalize + store
  float linv[2][4];
  #pragma unroll
  for (int mt = 0; mt < 2; mt++)
    #pragma unroll
    for (int r = 0; r < 4; r++) {
      float s = lsum[mt][r];
      s += __shfl_xor(s, 1); s += __shfl_xor(s, 2);
      s += __shfl_xor(s, 4); s += __shfl_xor(s, 8);
      linv[mt][r] = 1.0f / s;
    }
  #pragma unroll
  for (int mt = 0; mt < 2; mt++) {
    #pragma unroll
    for (int nt = 0; nt < 4; nt++) {
      #pragma unroll
      for (int r = 0; r < 4; r++) {
        int rg = n0 + w*32 + mt*16 + quad*4 + r;
        ctx[(size_t)(baseRow + rg) * 768 + h*64 + nt*16 + lane16] =
            f2bf(oacc[mt][nt][r] * linv[mt][r]);
      }
    }
  }
}

extern "C" void kernel_launch(void* const* d_in, const int* in_sizes, int n_in,
                              void* d_out, int out_size, void* d_ws, size_t ws_size,
                              hipStream_t stream) {
  const float* x     = (const float*)d_in[0];
  const int*   mask  = (const int*)d_in[1];
  const float* Wqkv  = (const float*)d_in[2];
  const float* Wproj = (const float*)d_in[3];
  const float* bproj = (const float*)d_in[4];
  float* out = (float*)d_out;

  const int NX = 8192 * 768;    // 6291456
  const int NQ = 2304 * 768;    // 1769472
  const int NP = 768 * 768;     // 589824

  char* wsb = (char*)d_ws;
  u16* qkv    = (u16*)wsb;                                  // 37.75 MB
  u16* ctx    = (u16*)(wsb + (size_t)8192 * 2304 * 2);      // 12.58 MB
  u16* xb     = (u16*)(wsb + (size_t)8192 * 2304 * 2 + (size_t)8192 * 768 * 2);
  u16* wqkvb  = xb + NX;
  u16* wprojb = wqkvb + NQ;

  int cvt_blocks = ((NX + NQ + NP) / 4 + 255) / 256;
  cvt_bf16<<<dim3(cvt_blocks), 256, 0, stream>>>(x, xb, NX, Wqkv, wqkvb, NQ, Wproj, wprojb, NP);

  gemm_bt<768, 2304, true><<<dim3(18, 64), 256, 0, stream>>>(xb, wqkvb, qkv, nullptr);
  attn_mfma<<<dim3(768), 256, 0, stream>>>(qkv, mask, ctx);
  gemm_bt<768, 768, false><<<dim3(6, 64), 256, 0, stream>>>(ctx, wprojb, out, bproj);
}